// Round 3
// baseline (1296.269 us; speedup 1.0000x reference)
//
#include <hip/hip_runtime.h>
#include <hip/hip_bf16.h>
#include <math.h>

// AttDecoder: V=32000 E=512 H=512 B=16 T=128 S=512 D=2
// d_out: [2048x32000 out][2048x1536 attention_input][2048 targets], dtype f32 OR bf16
// (runtime-detected via k_detect). Internal compute: bf16 MFMA, fp32 accum.

typedef __attribute__((ext_vector_type(8))) short short8;
typedef __attribute__((ext_vector_type(4))) float floatx4;
typedef __attribute__((ext_vector_type(4))) int intx4;
typedef __hip_bfloat16 bf16;

__device__ __forceinline__ float b2f(bf16 v){ return __bfloat162float(v); }
__device__ __forceinline__ bf16 f2b(float v){ return __float2bfloat16(v); }
// dual-dtype load: f32 flag chooses float vs bf16 interpretation
__device__ __forceinline__ float ld(const void* p, long i, int f32){
  return f32 ? ((const float*)p)[i] : b2f(((const bf16*)p)[i]);
}

// Sentinel: bf16 NaN pair. No finite float converts to this via f2b, and all
// LSTM h values are finite (products/sums of sigmoids/tanh of finite MFMA
// outputs), so real published data can never equal it.
#define SENTI ((int)0xFFC1FFC1u)

// device-scope 16B load (L1-bypass, IC-coherent) with its own drain — used
// only on the rare retry path.
__device__ __forceinline__ intx4 poll16(const void* pp){
  intx4 r;
  asm volatile("global_load_dwordx4 %0, %1, off sc0 sc1\n\ts_waitcnt vmcnt(0)"
               : "=v"(r) : "v"(pp) : "memory");
  return r;
}

// ------------------------------------------------------------- detect
__global__ void k_detect(const unsigned short* __restrict__ h0u, int* __restrict__ flags){
  if (threadIdx.x == 0){
    int bad = 0;
    for (int i=0;i<256;i++){
      int e = (h0u[i] >> 7) & 0xFF;
      if (e != 0 && (e < 100 || e > 140)) bad++;
    }
    flags[0] = (bad > 32) ? 1 : 0;   // 1 = inputs/outputs are float32
  }
}

// ---------------------------------------------------------------- prep
__global__ void k_prep(const int* __restrict__ x, const void* __restrict__ h0,
                       const void* __restrict__ c0, const void* __restrict__ emb,
                       const int* __restrict__ flags, bf16* __restrict__ lstm_input,
                       bf16* __restrict__ att_ws, float* __restrict__ state0,
                       bf16* __restrict__ hbuf){
  int f32 = flags[0];
  int idx = blockIdx.x*256 + threadIdx.x;    // 0 .. 2048*1024
  int m = idx >> 10, c = idx & 1023;
  float v;
  if (c < 512){
    int b = m >> 7;
    v = ld(h0, b*512 + c, f32) + ld(c0, b*512 + c, f32);
  } else {
    v = ld(emb, (long)x[m]*512 + (c - 512), f32);
  }
  bf16 bv = f2b(v);
  lstm_input[idx] = bv;
  att_ws[(long)m*1536 + 512 + c] = bv;
  if (idx < 8192){
    float hv = ld(h0, idx, f32), cv = ld(c0, idx, f32);
    hbuf[idx] = f2b(hv);                 // slot 0 of h history (real data)
    state0[idx] = hv;
    state0[8192 + idx] = cv;
  }
}

// --------------------------------------------------- sentinel-fill h slots 1..127
__global__ void k_sent(int* __restrict__ hbuf32){
  long i = (long)blockIdx.x*256 + threadIdx.x;   // 520,192 u32 = slots 1..127
  if (i < 520192) hbuf32[4096 + i] = SENTI;
}

// ---------------------------------------------------------- enc sum + T
__global__ void k_encT(const void* __restrict__ eo, const int* __restrict__ flags,
                       bf16* __restrict__ encT){
  __shared__ float tile[32][33];
  int f32 = flags[0];
  int b = blockIdx.z;
  int s0 = blockIdx.x*32, h0 = blockIdx.y*32;
  int tx = threadIdx.x, ty = threadIdx.y;   // (32,8)
  #pragma unroll
  for (int j=0;j<4;j++){
    int s = s0 + ty + j*8;
    long o = (long)b*262144 + (long)s*512 + h0 + tx;
    tile[ty + j*8][tx] = ld(eo, o, f32) + ld(eo, 4194304 + o, f32);
  }
  __syncthreads();
  #pragma unroll
  for (int j=0;j<4;j++){
    int h = h0 + ty + j*8;
    encT[((long)b*512 + h)*512 + s0 + tx] = f2b(tile[tx][ty + j*8]);
  }
}

// --------------------------------------------------------- transpose -> bf16
__global__ void k_tr(const void* __restrict__ in, bf16* __restrict__ out,
                     int R, int C, const int* __restrict__ flags){
  __shared__ float tile[32][33];
  int f32 = flags[0];
  int c0 = blockIdx.x*32, r0 = blockIdx.y*32;
  int tx = threadIdx.x, ty = threadIdx.y;   // (32,8)
  #pragma unroll
  for (int j=0;j<4;j++)
    tile[ty+j*8][tx] = ld(in, (long)(r0+ty+j*8)*C + c0+tx, f32);
  __syncthreads();
  #pragma unroll
  for (int j=0;j<4;j++)
    out[(long)(c0+ty+j*8)*R + r0+tx] = f2b(tile[tx][ty+j*8]);
}

// --------------------------------------------------------- flat convert
__global__ void k_cvtW(const void* __restrict__ w, const int* __restrict__ flags,
                       bf16* __restrict__ out, long n){
  int f32 = flags[0];
  long i = (long)blockIdx.x*256 + threadIdx.x;
  if (i < n) out[i] = f2b(ld(w, i, f32));
}

// biases -> bb: [0]=ih(2048) [2048]=hh(2048) [4096]=att(512) [4608]=align(512) [5120]=out(32000)
__global__ void k_cvt(const void* bih, const void* bhh, const void* batt,
                      const void* balign, const void* bout,
                      const int* __restrict__ flags, bf16* __restrict__ bb){
  int f32 = flags[0];
  int i = blockIdx.x*256 + threadIdx.x;
  if (i < 2048)      bb[i] = f2b(ld(bih, i, f32));
  else if (i < 4096) bb[i] = f2b(ld(bhh, i-2048, f32));
  else if (i < 4608) bb[i] = f2b(ld(batt, i-4096, f32));
  else if (i < 5120) bb[i] = f2b(ld(balign, i-4608, f32));
  else if (i < 37120) bb[i] = f2b(ld(bout, i-5120, f32));
}

// -------------------------------------------------- W_hh fragment swizzle
__global__ void k_wswz(const void* __restrict__ whh, const int* __restrict__ flags,
                       bf16* __restrict__ wsw){
  int f32 = flags[0];
  int bid = blockIdx.x;          // 2048
  int l = threadIdx.x;           // 64
  int p = bid >> 7, tt = (bid >> 4) & 7, ks = bid & 15;
  int g = tt >> 1, hh = tt & 1;
  int row = g*512 + p*32 + hh*16 + (l & 15);
  int k = ks*32 + (l >> 4)*8;
  #pragma unroll
  for (int j=0;j<8;j++)
    wsw[(long)(bid*64 + l)*8 + j] = f2b(ld(whh, (long)row*512 + k + j, f32));
}

// ---------------------------------------------------------------- GEMM
// NT: C[M,N] = A[M,K]*B[N,K]^T, A/B internal bf16 K-contiguous. 128x128 tile, BK=32.
#define M_GX    0
#define M_F32   1
#define M_BF16  2
#define M_ALIGN 3
#define M_OUT   4

template<int MODE>
__global__ void __launch_bounds__(256)
k_gemm(const bf16* __restrict__ A, const bf16* __restrict__ Bm, int K,
       float* __restrict__ outF, bf16* __restrict__ outBH, void* __restrict__ outO,
       int ldc, const bf16* __restrict__ bias1, const bf16* __restrict__ bias2,
       const bf16* __restrict__ alin, bf16* __restrict__ finin,
       const int* __restrict__ flags, long aZ, long bZ, long cZ){
  __shared__ __align__(16) bf16 As[128*32];
  __shared__ __align__(16) bf16 Bs[128*32];
  int dfl = 0;
  if constexpr (MODE == M_OUT) dfl = flags[0];
  int tid = threadIdx.x;
  int w = tid >> 6, l = tid & 63;
  int bm = blockIdx.x, bn = blockIdx.y, bz = blockIdx.z;
  const bf16* Ag = A + bz*aZ + (long)(bm*128 + (tid>>2))*K + (tid&3)*8;
  const bf16* Bg = Bm + bz*bZ + (long)(bn*128 + (tid>>2))*K + (tid&3)*8;
  int m0 = (w&1)*64, n0 = (w>>1)*64;
  floatx4 acc[4][4];
  #pragma unroll
  for (int i=0;i<4;i++)
    #pragma unroll
    for (int j=0;j<4;j++){ floatx4 z = {0.f,0.f,0.f,0.f}; acc[i][j] = z; }

  for (int k0=0; k0<K; k0+=32){
    short8 a0 = *(const short8*)(Ag + k0);
    short8 a1 = *(const short8*)(Ag + (long)64*K + k0);
    short8 b0 = *(const short8*)(Bg + k0);
    short8 b1 = *(const short8*)(Bg + (long)64*K + k0);
    __syncthreads();
    *(short8*)(As + tid*8)        = a0;
    *(short8*)(As + 2048 + tid*8) = a1;
    *(short8*)(Bs + tid*8)        = b0;
    *(short8*)(Bs + 2048 + tid*8) = b1;
    __syncthreads();
    short8 af[4], bfr[4];
    #pragma unroll
    for (int i=0;i<4;i++){
      af[i]  = *(const short8*)(As + (m0 + i*16 + (l&15))*32 + (l>>4)*8);
      bfr[i] = *(const short8*)(Bs + (n0 + i*16 + (l&15))*32 + (l>>4)*8);
    }
    #pragma unroll
    for (int i=0;i<4;i++)
      #pragma unroll
      for (int j=0;j<4;j++)
        acc[i][j] = __builtin_amdgcn_mfma_f32_16x16x32_bf16(af[i], bfr[j], acc[i][j], 0,0,0);
  }

  int rbase = (l>>4)*4;
  int cl = l & 15;
  #pragma unroll
  for (int i=0;i<4;i++){
    #pragma unroll
    for (int j=0;j<4;j++){
      int col = bn*128 + n0 + j*16 + cl;
      #pragma unroll
      for (int r=0;r<4;r++){
        int row = bm*128 + m0 + i*16 + rbase + r;
        float v = acc[i][j][r];
        if constexpr (MODE == M_GX){
          v += b2f(bias1[col]) + b2f(bias2[col]);
          int t = row & 127, b = row >> 7;
          outF[(long)(t*16 + b)*2048 + col] = v;
        } else if constexpr (MODE == M_F32){
          v += b2f(bias1[col]);
          outF[(long)row*ldc + col] = v;
        } else if constexpr (MODE == M_BF16){
          outBH[bz*cZ + (long)row*ldc + col] = f2b(v);
        } else if constexpr (MODE == M_ALIGN){
          v += b2f(bias1[col]);
          float sg = 1.0f/(1.0f + __expf(-v));
          float lo = b2f(alin[(long)row*1024 + col]);
          float hb = b2f(alin[(long)row*1024 + 512 + col]);
          finin[(long)row*512 + col] = f2b(lo + hb*sg);
        } else { // M_OUT
          v += b2f(bias1[col]);
          if (dfl) ((float*)outO)[(long)row*ldc + col] = v;
          else     ((bf16*)outO)[(long)row*ldc + col] = f2b(v);
        }
      }
    }
  }
}

// ------------------------------------------------------------- softmax
__global__ void k_softmax(const float* __restrict__ lg, bf16* __restrict__ soft){
  __shared__ float red[256];
  int r = blockIdx.x;
  int tid = threadIdx.x;
  float x0 = lg[(long)r*512 + tid], x1 = lg[(long)r*512 + 256 + tid];
  red[tid] = fmaxf(x0, x1); __syncthreads();
  for (int s=128; s>0; s>>=1){ if (tid<s) red[tid] = fmaxf(red[tid], red[tid+s]); __syncthreads(); }
  float mx = red[0]; __syncthreads();
  float e0 = __expf(x0-mx), e1 = __expf(x1-mx);
  red[tid] = e0+e1; __syncthreads();
  for (int s=128; s>0; s>>=1){ if (tid<s) red[tid] += red[tid+s]; __syncthreads(); }
  float inv = 1.0f/red[0];
  soft[(long)r*512 + tid] = f2b(e0*inv);
  soft[(long)r*512 + 256 + tid] = f2b(e1*inv);
}

// ------------------------------------------------------------- LSTM
// 16 blocks (one per 32-col slice of H), 128 sequential steps.
// Flagless exchange: h slots 1..127 are pre-filled with a bf16-NaN sentinel
// (k_sent). Writers publish their 16B chunks with sc0 sc1 stores and move on
// (no drain, no atomic, no barrier). Readers issue all 16 chunk loads in ONE
// asm block (pipelined, single vmcnt(0)), then retry only chunks still equal
// to the sentinel (all 4 dwords checked -> torn-store safe). Skew between
// blocks is bounded to 1 step by the data dependency itself; no spin can
// deadlock (it only waits on an already-issued store draining at device scope).
// W_hh fragments live in LDS (128KB slice, contiguous in wsw) instead of
// registers -- round-1's VGPR_Count=100 proved the 128-VGPR wfrag array was
// being spilled/rematerialized from global every step.
__global__ void __launch_bounds__(256, 1)
k_lstm(const float* __restrict__ gxT, const bf16* __restrict__ wsw,
       const int* __restrict__ xlen, const float* __restrict__ state0,
       bf16* __restrict__ hbuf, int* __restrict__ flags,
       bf16* __restrict__ att_ws, bf16* __restrict__ align_in){
  int p = blockIdx.x;
  int tid = threadIdx.x;
  int w = tid >> 6, l = tid & 63, w2 = w*2;
  __shared__ __align__(16) short8 wlds[8192];   // 128 KB W_hh fragment slice
  __shared__ float gx_sh[16*128];               // 8 KB
  __shared__ __align__(16) bf16 hsh[16*32];     // 1 KB
  __shared__ int lens[16];
  if (tid < 16) lens[tid] = xlen[tid];

  // stage this block's W_hh fragment slice (contiguous in wsw) into LDS
  {
    const short8* wsrc = (const short8*)wsw + (long)p*8192;
    #pragma unroll
    for (int i=0;i<32;i++) wlds[i*256 + tid] = wsrc[i*256 + tid];
  }

  int b0i = tid >> 5, u = tid & 31;
  int b1i = b0i + 8;
  float h_r0 = state0[b0i*512 + p*32 + u];
  float c_r0 = state0[8192 + b0i*512 + p*32 + u];
  float h_r1 = state0[b1i*512 + p*32 + u];
  float c_r1 = state0[8192 + b1i*512 + p*32 + u];

  // prefetch gx for t=0
  float gr[8];
  #pragma unroll
  for (int rep=0;rep<8;rep++){
    int idx = rep*256 + tid;
    int b = idx >> 7, jl = idx & 127;
    gr[rep] = gxT[(long)b*2048 + (jl>>5)*512 + p*32 + (jl&31)];
  }

  __syncthreads();   // wlds + lens ready

  for (int t=0; t<128; t++){
    // (a) prefetched gx -> LDS
    #pragma unroll
    for (int rep=0;rep<8;rep++)
      gx_sh[rep*256 + tid] = gr[rep];

    // (poll) all 16 h chunks of slot t in one pipelined asm block
    const char* hbp = (const char*)hbuf + (long)t*16384 + ((l&15)*1024 + (l>>4)*16);
    intx4 a0,a1,a2,a3,a4,a5,a6,a7,a8,a9,a10,a11,a12,a13,a14,a15;
    asm volatile(
      "global_load_dwordx4 %0,  %16, off sc0 sc1\n\t"
      "global_load_dwordx4 %1,  %16, off offset:64  sc0 sc1\n\t"
      "global_load_dwordx4 %2,  %16, off offset:128 sc0 sc1\n\t"
      "global_load_dwordx4 %3,  %16, off offset:192 sc0 sc1\n\t"
      "global_load_dwordx4 %4,  %16, off offset:256 sc0 sc1\n\t"
      "global_load_dwordx4 %5,  %16, off offset:320 sc0 sc1\n\t"
      "global_load_dwordx4 %6,  %16, off offset:384 sc0 sc1\n\t"
      "global_load_dwordx4 %7,  %16, off offset:448 sc0 sc1\n\t"
      "global_load_dwordx4 %8,  %16, off offset:512 sc0 sc1\n\t"
      "global_load_dwordx4 %9,  %16, off offset:576 sc0 sc1\n\t"
      "global_load_dwordx4 %10, %16, off offset:640 sc0 sc1\n\t"
      "global_load_dwordx4 %11, %16, off offset:704 sc0 sc1\n\t"
      "global_load_dwordx4 %12, %16, off offset:768 sc0 sc1\n\t"
      "global_load_dwordx4 %13, %16, off offset:832 sc0 sc1\n\t"
      "global_load_dwordx4 %14, %16, off offset:896 sc0 sc1\n\t"
      "global_load_dwordx4 %15, %16, off offset:960 sc0 sc1\n\t"
      "s_waitcnt vmcnt(0)"
      : "=v"(a0),"=v"(a1),"=v"(a2),"=v"(a3),"=v"(a4),"=v"(a5),"=v"(a6),"=v"(a7),
        "=v"(a8),"=v"(a9),"=v"(a10),"=v"(a11),"=v"(a12),"=v"(a13),"=v"(a14),"=v"(a15)
      : "v"(hbp)
      : "memory");
    #define RETRY(A, OFF) \
      while (__builtin_expect(A.x==SENTI || A.y==SENTI || A.z==SENTI || A.w==SENTI, 0)) \
        A = poll16(hbp + (OFF));
    RETRY(a0,0)    RETRY(a1,64)   RETRY(a2,128)  RETRY(a3,192)
    RETRY(a4,256)  RETRY(a5,320)  RETRY(a6,384)  RETRY(a7,448)
    RETRY(a8,512)  RETRY(a9,576)  RETRY(a10,640) RETRY(a11,704)
    RETRY(a12,768) RETRY(a13,832) RETRY(a14,896) RETRY(a15,960)
    #undef RETRY

    // (b) issue prefetch of next step's gx (consumed next iteration)
    if (t < 127){
      #pragma unroll
      for (int rep=0;rep<8;rep++){
        int idx = rep*256 + tid;
        int b = idx >> 7, jl = idx & 127;
        gr[rep] = gxT[(long)((t+1)*16 + b)*2048 + (jl>>5)*512 + p*32 + (jl&31)];
      }
    }

    // (c) MFMA: h chunks (registers) x W_hh fragments (LDS)
    floatx4 acc0 = {0.f,0.f,0.f,0.f};
    floatx4 acc1 = {0.f,0.f,0.f,0.f};
    #define STEPK(K, AK) { \
      short8 av = __builtin_bit_cast(short8, AK); \
      acc0 = __builtin_amdgcn_mfma_f32_16x16x32_bf16(av, wlds[(w2*16+(K))*64 + l], acc0, 0,0,0); \
      acc1 = __builtin_amdgcn_mfma_f32_16x16x32_bf16(av, wlds[((w2+1)*16+(K))*64 + l], acc1, 0,0,0); }
    STEPK(0,a0)   STEPK(1,a1)   STEPK(2,a2)   STEPK(3,a3)
    STEPK(4,a4)   STEPK(5,a5)   STEPK(6,a6)   STEPK(7,a7)
    STEPK(8,a8)   STEPK(9,a9)   STEPK(10,a10) STEPK(11,a11)
    STEPK(12,a12) STEPK(13,a13) STEPK(14,a14) STEPK(15,a15)
    #undef STEPK
    __syncthreads();

    // (d) accumulate fragments into gates
    #pragma unroll
    for (int r=0; r<4; r++){
      int bb = (l>>4)*4 + r;
      gx_sh[bb*128 + w*32 + (l&15)]      += acc0[r];
      gx_sh[bb*128 + w*32 + 16 + (l&15)] += acc1[r];
    }
    __syncthreads();

    // (e) activations: 2 batches per thread
    {
      float ig = gx_sh[b0i*128 + u],      fg = gx_sh[b0i*128 + 32 + u];
      float gg = gx_sh[b0i*128 + 64 + u], og = gx_sh[b0i*128 + 96 + u];
      bool valid = (t < lens[b0i]);
      float ii = 1.f/(1.f+__expf(-ig)), ff = 1.f/(1.f+__expf(-fg));
      float g2 = tanhf(gg),             oo = 1.f/(1.f+__expf(-og));
      float cn = ff*c_r0 + ii*g2;
      float hn = oo*tanhf(cn);
      if (valid){ c_r0 = cn; h_r0 = hn; }
      float hout = valid ? hn : 0.0f;
      hsh[b0i*32 + u] = f2b(h_r0);
      int row = b0i*128 + t;
      att_ws[(long)row*1536 + p*32 + u]   = f2b(hout);
      align_in[(long)row*1024 + p*32 + u] = f2b(hout);
    }
    {
      float ig = gx_sh[b1i*128 + u],      fg = gx_sh[b1i*128 + 32 + u];
      float gg = gx_sh[b1i*128 + 64 + u], og = gx_sh[b1i*128 + 96 + u];
      bool valid = (t < lens[b1i]);
      float ii = 1.f/(1.f+__expf(-ig)), ff = 1.f/(1.f+__expf(-fg));
      float g2 = tanhf(gg),             oo = 1.f/(1.f+__expf(-og));
      float cn = ff*c_r1 + ii*g2;
      float hn = oo*tanhf(cn);
      if (valid){ c_r1 = cn; h_r1 = hn; }
      float hout = valid ? hn : 0.0f;
      hsh[b1i*32 + u] = f2b(h_r1);
      int row = b1i*128 + t;
      att_ws[(long)row*1536 + p*32 + u]   = f2b(hout);
      align_in[(long)row*1024 + p*32 + u] = f2b(hout);
    }
    __syncthreads();   // hsh ready

    // (f) publish h slice to slot t+1: fire-and-forget device-visible stores
    if (t < 127 && tid < 64){
      int b = tid >> 2, ch = tid & 3;
      intx4 hv = *(const intx4*)(hsh + b*32 + ch*8);
      bf16* dst = hbuf + (long)(t+1)*8192 + b*512 + p*32 + ch*8;
      asm volatile("global_store_dwordx4 %0, %1, off sc0 sc1" :: "v"(dst), "v"(hv) : "memory");
    }
  }
}

// ---------------------------------------------------- final att/targets out
__global__ void k_finout(const bf16* __restrict__ att_ws, const int* __restrict__ flags,
                         void* __restrict__ d_out){
  int f32 = flags[0];
  long i = (long)blockIdx.x*256 + threadIdx.x;  // 3,147,776 total
  if (i < 3145728){
    if (f32) ((float*)d_out)[65536000 + i] = b2f(att_ws[i]);
    else     ((bf16*)d_out)[65536000 + i] = att_ws[i];
  } else if (i < 3147776){
    long j = i - 3145728;
    float tv = (float)(4*((int)j & 127));
    if (f32) ((float*)d_out)[68681728 + j] = tv;
    else     ((bf16*)d_out)[68681728 + j] = f2b(tv);
  }
}

// ---------------------------------------------------------------- launch
extern "C" void kernel_launch(void* const* d_in, const int* in_sizes, int n_in,
                              void* d_out, int out_size, void* d_ws, size_t ws_size,
                              hipStream_t stream){
  const int*  x      = (const int*) d_in[0];
  const int*  xlen   = (const int*) d_in[1];
  const void* h0     = d_in[2];
  const void* c0     = d_in[3];
  const void* eo     = d_in[4];
  const void* emb    = d_in[5];
  const void* W_att  = d_in[6];
  const void* b_att  = d_in[7];
  const void* W_ih   = d_in[8];
  const void* W_hh   = d_in[9];
  const void* b_ih   = d_in[10];
  const void* b_hh   = d_in[11];
  const void* W_align= d_in[12];
  const void* b_align= d_in[13];
  const void* W_out  = d_in[14];
  const void* b_out  = d_in[15];

  char* ws = (char*)d_ws;
  bf16*  lstm_input = (bf16*)(ws + 0);            //  4,194,304
  bf16*  encT       = (bf16*)(ws + 4194304);      //  8,388,608
  bf16*  WattT      = (bf16*)(ws + 12582912);     //  1,572,864
  bf16*  WalignT    = (bf16*)(ws + 14155776);     //  1,048,576
  bf16*  WoutT      = (bf16*)(ws + 15204352);     // 32,768,000
  bf16*  Wsw        = (bf16*)(ws + 47972352);     //  2,097,152
  float* gxT        = (float*)(ws + 50069504);    // 16,777,216
  float* attlog     = (float*)(ws + 66846720);    //  4,194,304
  bf16*  soft       = (bf16*)(ws + 71041024);     //  2,097,152
  bf16*  align_in   = (bf16*)(ws + 73138176);     //  4,194,304
  // h history (128 slots x 16KB = 2MB) shares the final_in region:
  // written by k_prep (slot0) + k_sent (sentinels) + k_lstm; final_in is
  // produced only AFTER k_lstm by the M_ALIGN gemm -> lifetimes disjoint.
  bf16*  final_in   = (bf16*)(ws + 77332480);     //  2,097,152
  bf16*  hbuf       = (bf16*)(ws + 77332480);     //  (aliases final_in)
  bf16*  att_ws     = (bf16*)(ws + 79429632);     //  6,291,456
  bf16*  bb         = (bf16*)(ws + 85721088);     //     74,240
  float* state0     = (float*)(ws + 85795328);    //     65,536
  bf16*  WihB       = (bf16*)(ws + 85893632);     //  4,194,304
  int*   flags      = (int*) (ws + 90087936);     // total ~90.1 MB

  k_detect<<<1, 64, 0, stream>>>((const unsigned short*)h0, flags);
  k_prep<<<8192, 256, 0, stream>>>(x, h0, c0, emb, flags, lstm_input, att_ws, state0, hbuf);
  k_sent<<<2032, 256, 0, stream>>>((int*)hbuf);
  k_cvt<<<146, 256, 0, stream>>>(b_ih, b_hh, b_att, b_align, b_out, flags, bb);
  k_cvtW<<<8192, 256, 0, stream>>>(W_ih, flags, WihB, 2097152L);
  k_encT<<<dim3(16,16,16), dim3(32,8), 0, stream>>>(eo, flags, encT);
  k_tr<<<dim3(16,48),  dim3(32,8), 0, stream>>>(W_att,   WattT,   1536, 512, flags);
  k_tr<<<dim3(16,32),  dim3(32,8), 0, stream>>>(W_align, WalignT, 1024, 512, flags);
  k_tr<<<dim3(1000,16),dim3(32,8), 0, stream>>>(W_out,   WoutT,   512, 32000, flags);
  k_wswz<<<2048, 64, 0, stream>>>(W_hh, flags, Wsw);

  // gates_x = lstm_input @ W_ih^T + b_ih + b_hh  -> gxT[t*16+b][2048] f32
  k_gemm<M_GX><<<dim3(16,16,1), 256, 0, stream>>>(lstm_input, WihB, 1024,
      gxT, nullptr, nullptr, 0, bb, bb+2048, nullptr, nullptr, flags, 0, 0, 0);

  k_lstm<<<16, 256, 0, stream>>>(gxT, Wsw, xlen, state0, hbuf, flags, att_ws, align_in);

  // att_logits = attention_input @ W_att + b_att  (f32)
  k_gemm<M_F32><<<dim3(16,4,1), 256, 0, stream>>>(att_ws, WattT, 1536,
      attlog, nullptr, nullptr, 512, bb+4096, nullptr, nullptr, nullptr, flags, 0, 0, 0);

  k_softmax<<<2048, 256, 0, stream>>>(attlog, soft);

  // h_t_bar[b] = soft[b] @ enc[b]  -> align_in cols 512:1024
  k_gemm<M_BF16><<<dim3(1,4,16), 256, 0, stream>>>(soft, encT, 512,
      nullptr, align_in + 512, nullptr, 1024, nullptr, nullptr, nullptr, nullptr,
      flags, 65536L, 262144L, 131072L);

  // aligned = sigmoid(align_in @ W_align + b_align); final_in = lo + hb*aligned
  k_gemm<M_ALIGN><<<dim3(16,4,1), 256, 0, stream>>>(align_in, WalignT, 1024,
      nullptr, nullptr, nullptr, 0, bb+4608, nullptr, align_in, final_in, flags, 0, 0, 0);

  // out = final_in @ W_out + b_out
  k_gemm<M_OUT><<<dim3(16,250,1), 256, 0, stream>>>(final_in, WoutT, 512,
      nullptr, nullptr, d_out, 32000, bb+5120, nullptr, nullptr, nullptr, flags, 0, 0, 0);

  k_finout<<<12296, 256, 0, stream>>>(att_ws, flags, d_out);
}

// Round 4
// 1172.389 us; speedup vs baseline: 1.1057x; 1.1057x over previous
//
#include <hip/hip_runtime.h>
#include <hip/hip_bf16.h>
#include <math.h>

// AttDecoder: V=32000 E=512 H=512 B=16 T=128 S=512 D=2
// d_out: [2048x32000 out][2048x1536 attention_input][2048 targets], dtype f32 OR bf16
// (runtime-detected via k_detect). Internal compute: bf16 MFMA, fp32 accum.

typedef __attribute__((ext_vector_type(8))) short short8;
typedef __attribute__((ext_vector_type(4))) float floatx4;
typedef __attribute__((ext_vector_type(4))) int intx4;
typedef __hip_bfloat16 bf16;

__device__ __forceinline__ float b2f(bf16 v){ return __bfloat162float(v); }
__device__ __forceinline__ bf16 f2b(float v){ return __float2bfloat16(v); }
// dual-dtype load: f32 flag chooses float vs bf16 interpretation
__device__ __forceinline__ float ld(const void* p, long i, int f32){
  return f32 ? ((const float*)p)[i] : b2f(((const bf16*)p)[i]);
}
// fast tanh via single __expf: 1 - 2/(e^{2x}+1); exact at +-inf, ~1e-7 rel err
__device__ __forceinline__ float ftanh(float x){
  float e = __expf(2.0f*x);
  return 1.0f - 2.0f/(e + 1.0f);
}

// Sentinel: bf16 NaN pair. No finite float converts to this via f2b, and all
// LSTM h values are finite, so real published data can never equal it.
#define SENTI ((int)0xFFC1FFC1u)

// 16B retry load; fast=1 -> XCD-local (sc0, L2-scope), else device (sc0 sc1).
__device__ __forceinline__ intx4 poll16(const void* pp, int fast){
  intx4 r;
  if (fast)
    asm volatile("global_load_dwordx4 %0, %1, off sc0\n\ts_waitcnt vmcnt(0)"
                 : "=v"(r) : "v"(pp) : "memory");
  else
    asm volatile("global_load_dwordx4 %0, %1, off sc0 sc1\n\ts_waitcnt vmcnt(0)"
                 : "=v"(r) : "v"(pp) : "memory");
  return r;
}

__device__ __forceinline__ long rdclk(){
  long v; asm volatile("s_memtime %0\n\ts_waitcnt lgkmcnt(0)" : "=s"(v)); return v;
}

// flags layout (ints): [0]=f32 detect; [128..143]=handshake tokens; [192]=verdict acc
// ------------------------------------------------------------- detect
__global__ void k_detect(const unsigned short* __restrict__ h0u, int* __restrict__ flags){
  if (threadIdx.x == 0){
    int bad = 0;
    for (int i=0;i<256;i++){
      int e = (h0u[i] >> 7) & 0xFF;
      if (e != 0 && (e < 100 || e > 140)) bad++;
    }
    flags[0] = (bad > 32) ? 1 : 0;   // 1 = inputs/outputs are float32
    for (int i=0;i<16;i++) flags[128+i] = 0;
    flags[192] = 0;
  }
}

// ---------------------------------------------------------------- prep
__global__ void k_prep(const int* __restrict__ x, const void* __restrict__ h0,
                       const void* __restrict__ c0, const void* __restrict__ emb,
                       const int* __restrict__ flags, bf16* __restrict__ lstm_input,
                       bf16* __restrict__ att_ws, float* __restrict__ state0,
                       bf16* __restrict__ hbuf){
  int f32 = flags[0];
  int idx = blockIdx.x*256 + threadIdx.x;    // 0 .. 2048*1024
  int m = idx >> 10, c = idx & 1023;
  float v;
  if (c < 512){
    int b = m >> 7;
    v = ld(h0, b*512 + c, f32) + ld(c0, b*512 + c, f32);
  } else {
    v = ld(emb, (long)x[m]*512 + (c - 512), f32);
  }
  bf16 bv = f2b(v);
  lstm_input[idx] = bv;
  att_ws[(long)m*1536 + 512 + c] = bv;
  if (idx < 8192){
    float hv = ld(h0, idx, f32), cv = ld(c0, idx, f32);
    hbuf[idx] = f2b(hv);                 // slot 0 of h history (real data)
    state0[idx] = hv;
    state0[8192 + idx] = cv;
  }
}

// --------------------------------------------------- sentinel-fill h slots 1..127
__global__ void k_sent(int* __restrict__ hbuf32){
  long i = (long)blockIdx.x*256 + threadIdx.x;   // 520,192 u32 = slots 1..127
  if (i < 520192) hbuf32[4096 + i] = SENTI;
}

// ---------------------------------------------------------- enc sum + T
__global__ void k_encT(const void* __restrict__ eo, const int* __restrict__ flags,
                       bf16* __restrict__ encT){
  __shared__ float tile[32][33];
  int f32 = flags[0];
  int b = blockIdx.z;
  int s0 = blockIdx.x*32, h0 = blockIdx.y*32;
  int tx = threadIdx.x, ty = threadIdx.y;   // (32,8)
  #pragma unroll
  for (int j=0;j<4;j++){
    int s = s0 + ty + j*8;
    long o = (long)b*262144 + (long)s*512 + h0 + tx;
    tile[ty + j*8][tx] = ld(eo, o, f32) + ld(eo, 4194304 + o, f32);
  }
  __syncthreads();
  #pragma unroll
  for (int j=0;j<4;j++){
    int h = h0 + ty + j*8;
    encT[((long)b*512 + h)*512 + s0 + tx] = f2b(tile[tx][ty + j*8]);
  }
}

// --------------------------------------------------------- transpose -> bf16
__global__ void k_tr(const void* __restrict__ in, bf16* __restrict__ out,
                     int R, int C, const int* __restrict__ flags){
  __shared__ float tile[32][33];
  int f32 = flags[0];
  int c0 = blockIdx.x*32, r0 = blockIdx.y*32;
  int tx = threadIdx.x, ty = threadIdx.y;   // (32,8)
  #pragma unroll
  for (int j=0;j<4;j++)
    tile[ty+j*8][tx] = ld(in, (long)(r0+ty+j*8)*C + c0+tx, f32);
  __syncthreads();
  #pragma unroll
  for (int j=0;j<4;j++)
    out[(long)(c0+ty+j*8)*R + r0+tx] = f2b(tile[tx][ty+j*8]);
}

// --------------------------------------------------------- flat convert
__global__ void k_cvtW(const void* __restrict__ w, const int* __restrict__ flags,
                       bf16* __restrict__ out, long n){
  int f32 = flags[0];
  long i = (long)blockIdx.x*256 + threadIdx.x;
  if (i < n) out[i] = f2b(ld(w, i, f32));
}

// biases -> bb: [0]=ih(2048) [2048]=hh(2048) [4096]=att(512) [4608]=align(512) [5120]=out(32000)
__global__ void k_cvt(const void* bih, const void* bhh, const void* batt,
                      const void* balign, const void* bout,
                      const int* __restrict__ flags, bf16* __restrict__ bb){
  int f32 = flags[0];
  int i = blockIdx.x*256 + threadIdx.x;
  if (i < 2048)      bb[i] = f2b(ld(bih, i, f32));
  else if (i < 4096) bb[i] = f2b(ld(bhh, i-2048, f32));
  else if (i < 4608) bb[i] = f2b(ld(batt, i-4096, f32));
  else if (i < 5120) bb[i] = f2b(ld(balign, i-4608, f32));
  else if (i < 37120) bb[i] = f2b(ld(bout, i-5120, f32));
}

// -------------------------------------------------- W_hh fragment swizzle
__global__ void k_wswz(const void* __restrict__ whh, const int* __restrict__ flags,
                       bf16* __restrict__ wsw){
  int f32 = flags[0];
  int bid = blockIdx.x;          // 2048
  int l = threadIdx.x;           // 64
  int p = bid >> 7, tt = (bid >> 4) & 7, ks = bid & 15;
  int g = tt >> 1, hh = tt & 1;
  int row = g*512 + p*32 + hh*16 + (l & 15);
  int k = ks*32 + (l >> 4)*8;
  #pragma unroll
  for (int j=0;j<8;j++)
    wsw[(long)(bid*64 + l)*8 + j] = f2b(ld(whh, (long)row*512 + k + j, f32));
}

// ---------------------------------------------------------------- GEMM
// NT: C[M,N] = A[M,K]*B[N,K]^T, A/B internal bf16 K-contiguous. 128x128 tile, BK=32.
#define M_GX    0
#define M_F32   1
#define M_BF16  2
#define M_ALIGN 3
#define M_OUT   4

template<int MODE>
__global__ void __launch_bounds__(256)
k_gemm(const bf16* __restrict__ A, const bf16* __restrict__ Bm, int K,
       float* __restrict__ outF, bf16* __restrict__ outBH, void* __restrict__ outO,
       int ldc, const bf16* __restrict__ bias1, const bf16* __restrict__ bias2,
       const bf16* __restrict__ alin, bf16* __restrict__ finin,
       const int* __restrict__ flags, long aZ, long bZ, long cZ){
  __shared__ __align__(16) bf16 As[128*32];
  __shared__ __align__(16) bf16 Bs[128*32];
  int dfl = 0;
  if constexpr (MODE == M_OUT) dfl = flags[0];
  int tid = threadIdx.x;
  int w = tid >> 6, l = tid & 63;
  int bm = blockIdx.x, bn = blockIdx.y, bz = blockIdx.z;
  const bf16* Ag = A + bz*aZ + (long)(bm*128 + (tid>>2))*K + (tid&3)*8;
  const bf16* Bg = Bm + bz*bZ + (long)(bn*128 + (tid>>2))*K + (tid&3)*8;
  int m0 = (w&1)*64, n0 = (w>>1)*64;
  floatx4 acc[4][4];
  #pragma unroll
  for (int i=0;i<4;i++)
    #pragma unroll
    for (int j=0;j<4;j++){ floatx4 z = {0.f,0.f,0.f,0.f}; acc[i][j] = z; }

  for (int k0=0; k0<K; k0+=32){
    short8 a0 = *(const short8*)(Ag + k0);
    short8 a1 = *(const short8*)(Ag + (long)64*K + k0);
    short8 b0 = *(const short8*)(Bg + k0);
    short8 b1 = *(const short8*)(Bg + (long)64*K + k0);
    __syncthreads();
    *(short8*)(As + tid*8)        = a0;
    *(short8*)(As + 2048 + tid*8) = a1;
    *(short8*)(Bs + tid*8)        = b0;
    *(short8*)(Bs + 2048 + tid*8) = b1;
    __syncthreads();
    short8 af[4], bfr[4];
    #pragma unroll
    for (int i=0;i<4;i++){
      af[i]  = *(const short8*)(As + (m0 + i*16 + (l&15))*32 + (l>>4)*8);
      bfr[i] = *(const short8*)(Bs + (n0 + i*16 + (l&15))*32 + (l>>4)*8);
    }
    #pragma unroll
    for (int i=0;i<4;i++)
      #pragma unroll
      for (int j=0;j<4;j++)
        acc[i][j] = __builtin_amdgcn_mfma_f32_16x16x32_bf16(af[i], bfr[j], acc[i][j], 0,0,0);
  }

  int rbase = (l>>4)*4;
  int cl = l & 15;
  #pragma unroll
  for (int i=0;i<4;i++){
    #pragma unroll
    for (int j=0;j<4;j++){
      int col = bn*128 + n0 + j*16 + cl;
      #pragma unroll
      for (int r=0;r<4;r++){
        int row = bm*128 + m0 + i*16 + rbase + r;
        float v = acc[i][j][r];
        if constexpr (MODE == M_GX){
          v += b2f(bias1[col]) + b2f(bias2[col]);
          int t = row & 127, b = row >> 7;
          outF[(long)(t*16 + b)*2048 + col] = v;
        } else if constexpr (MODE == M_F32){
          v += b2f(bias1[col]);
          outF[(long)row*ldc + col] = v;
        } else if constexpr (MODE == M_BF16){
          outBH[bz*cZ + (long)row*ldc + col] = f2b(v);
        } else if constexpr (MODE == M_ALIGN){
          v += b2f(bias1[col]);
          float sg = 1.0f/(1.0f + __expf(-v));
          float lo = b2f(alin[(long)row*1024 + col]);
          float hb = b2f(alin[(long)row*1024 + 512 + col]);
          finin[(long)row*512 + col] = f2b(lo + hb*sg);
        } else { // M_OUT
          v += b2f(bias1[col]);
          if (dfl) ((float*)outO)[(long)row*ldc + col] = v;
          else     ((bf16*)outO)[(long)row*ldc + col] = f2b(v);
        }
      }
    }
  }
}

// ------------------------------------------------------------- softmax
__global__ void k_softmax(const float* __restrict__ lg, bf16* __restrict__ soft){
  __shared__ float red[256];
  int r = blockIdx.x;
  int tid = threadIdx.x;
  float x0 = lg[(long)r*512 + tid], x1 = lg[(long)r*512 + 256 + tid];
  red[tid] = fmaxf(x0, x1); __syncthreads();
  for (int s=128; s>0; s>>=1){ if (tid<s) red[tid] = fmaxf(red[tid], red[tid+s]); __syncthreads(); }
  float mx = red[0]; __syncthreads();
  float e0 = __expf(x0-mx), e1 = __expf(x1-mx);
  red[tid] = e0+e1; __syncthreads();
  for (int s=128; s>0; s>>=1){ if (tid<s) red[tid] += red[tid+s]; __syncthreads(); }
  float inv = 1.0f/red[0];
  soft[(long)r*512 + tid] = f2b(e0*inv);
  soft[(long)r*512 + 256 + tid] = f2b(e1*inv);
}

// ------------------------------------------------------------- LSTM
// Workers = blocks {0,16,...,240} of a 256-block grid. Under the round-robin
// blockIdx%8 -> XCD mapping these 16 blocks land on ONE XCD, making the
// per-step h exchange L2-local (~200cy) instead of Infinity-Cache (~700cy+).
// We do NOT trust that mapping: a one-time empirical handshake (sc0-only
// token stores/polls with s_memtime timeout, verdicts AND-reduced through the
// proven agent-scope atomic channel) decides fast (sc0-only) vs slow
// (sc0 sc1, round-3-verified) exchange. No path can hang: the token poll is
// timeout-bounded; the agreement spin waits only on unconditional adds.
// Per-step protocol is the flagless sentinel scheme of round 3.
__global__ void __launch_bounds__(256, 1)
k_lstm(const float* __restrict__ gxT, const bf16* __restrict__ wsw,
       const int* __restrict__ xlen, const float* __restrict__ state0,
       bf16* __restrict__ hbuf, int* __restrict__ flags,
       bf16* __restrict__ att_ws, bf16* __restrict__ align_in){
  int bid = blockIdx.x;
  if (bid & 15) return;          // 16 workers: 0,16,...,240
  int p = bid >> 4;
  int tid = threadIdx.x;
  int w = tid >> 6, l = tid & 63, w2 = w*2;
  __shared__ __align__(16) short8 wlds[8192];   // 128 KB W_hh fragment slice
  __shared__ float gx_sh[16*128];               // 8 KB
  __shared__ __align__(16) bf16 hsh[16*32];     // 1 KB
  __shared__ int lens[16];
  __shared__ int fastsh;
  if (tid < 16) lens[tid] = xlen[tid];

  // ---- one-time co-XCD handshake (tid 0) ----
  if (tid == 0){
    int one = 1;
    int* tok = flags + 128 + p;
    asm volatile("global_store_dword %0, %1, off sc0" :: "v"(tok), "v"(one) : "memory");
    long t0 = rdclk();
    int ok = 0;
    for(;;){
      intx4 h0v,h1v,h2v,h3v;
      asm volatile(
        "global_load_dwordx4 %0, %4, off sc0\n\t"
        "global_load_dwordx4 %1, %4, off offset:16 sc0\n\t"
        "global_load_dwordx4 %2, %4, off offset:32 sc0\n\t"
        "global_load_dwordx4 %3, %4, off offset:48 sc0\n\t"
        "s_waitcnt vmcnt(0)"
        : "=v"(h0v),"=v"(h1v),"=v"(h2v),"=v"(h3v) : "v"(flags+128) : "memory");
      int a = h0v.x&h0v.y&h0v.z&h0v.w & h1v.x&h1v.y&h1v.z&h1v.w
            & h2v.x&h2v.y&h2v.z&h2v.w & h3v.x&h3v.y&h3v.z&h3v.w;
      if (a == 1){ ok = 1; break; }
      if (rdclk() - t0 > 400000) break;   // ~0.17ms bound (any clock source)
    }
    __hip_atomic_fetch_add(flags+192, ok ? 1 : 0x10000,
                           __ATOMIC_RELAXED, __HIP_MEMORY_SCOPE_AGENT);
    int c;
    for(;;){
      c = __hip_atomic_load(flags+192, __ATOMIC_RELAXED, __HIP_MEMORY_SCOPE_AGENT);
      if (((c & 0xFFFF) + (c >> 16)) >= 16) break;
      __builtin_amdgcn_s_sleep(2);
    }
    fastsh = ((c >> 16) == 0) ? 1 : 0;
  }

  // stage this block's W_hh fragment slice (contiguous in wsw) into LDS
  {
    const short8* wsrc = (const short8*)wsw + (long)p*8192;
    #pragma unroll
    for (int i=0;i<32;i++) wlds[i*256 + tid] = wsrc[i*256 + tid];
  }

  int b0i = tid >> 5, u = tid & 31;
  int b1i = b0i + 8;
  float h_r0 = state0[b0i*512 + p*32 + u];
  float c_r0 = state0[8192 + b0i*512 + p*32 + u];
  float h_r1 = state0[b1i*512 + p*32 + u];
  float c_r1 = state0[8192 + b1i*512 + p*32 + u];

  // prefetch gx for t=0
  float gr[8];
  #pragma unroll
  for (int rep=0;rep<8;rep++){
    int idx = rep*256 + tid;
    int b = idx >> 7, jl = idx & 127;
    gr[rep] = gxT[(long)b*2048 + (jl>>5)*512 + p*32 + (jl&31)];
  }

  __syncthreads();   // wlds + lens + fastsh ready
  const int fast = fastsh;

  for (int t=0; t<128; t++){
    // (a) prefetched gx -> LDS
    #pragma unroll
    for (int rep=0;rep<8;rep++)
      gx_sh[rep*256 + tid] = gr[rep];

    // (poll) all 16 h chunks of slot t in one pipelined asm block
    const char* hbp = (const char*)hbuf + (long)t*16384 + ((l&15)*1024 + (l>>4)*16);
    intx4 a0,a1,a2,a3,a4,a5,a6,a7,a8,a9,a10,a11,a12,a13,a14,a15;
    if (fast){
      asm volatile(
        "global_load_dwordx4 %0,  %16, off sc0\n\t"
        "global_load_dwordx4 %1,  %16, off offset:64  sc0\n\t"
        "global_load_dwordx4 %2,  %16, off offset:128 sc0\n\t"
        "global_load_dwordx4 %3,  %16, off offset:192 sc0\n\t"
        "global_load_dwordx4 %4,  %16, off offset:256 sc0\n\t"
        "global_load_dwordx4 %5,  %16, off offset:320 sc0\n\t"
        "global_load_dwordx4 %6,  %16, off offset:384 sc0\n\t"
        "global_load_dwordx4 %7,  %16, off offset:448 sc0\n\t"
        "global_load_dwordx4 %8,  %16, off offset:512 sc0\n\t"
        "global_load_dwordx4 %9,  %16, off offset:576 sc0\n\t"
        "global_load_dwordx4 %10, %16, off offset:640 sc0\n\t"
        "global_load_dwordx4 %11, %16, off offset:704 sc0\n\t"
        "global_load_dwordx4 %12, %16, off offset:768 sc0\n\t"
        "global_load_dwordx4 %13, %16, off offset:832 sc0\n\t"
        "global_load_dwordx4 %14, %16, off offset:896 sc0\n\t"
        "global_load_dwordx4 %15, %16, off offset:960 sc0\n\t"
        "s_waitcnt vmcnt(0)"
        : "=v"(a0),"=v"(a1),"=v"(a2),"=v"(a3),"=v"(a4),"=v"(a5),"=v"(a6),"=v"(a7),
          "=v"(a8),"=v"(a9),"=v"(a10),"=v"(a11),"=v"(a12),"=v"(a13),"=v"(a14),"=v"(a15)
        : "v"(hbp)
        : "memory");
    } else {
      asm volatile(
        "global_load_dwordx4 %0,  %16, off sc0 sc1\n\t"
        "global_load_dwordx4 %1,  %16, off offset:64  sc0 sc1\n\t"
        "global_load_dwordx4 %2,  %16, off offset:128 sc0 sc1\n\t"
        "global_load_dwordx4 %3,  %16, off offset:192 sc0 sc1\n\t"
        "global_load_dwordx4 %4,  %16, off offset:256 sc0 sc1\n\t"
        "global_load_dwordx4 %5,  %16, off offset:320 sc0 sc1\n\t"
        "global_load_dwordx4 %6,  %16, off offset:384 sc0 sc1\n\t"
        "global_load_dwordx4 %7,  %16, off offset:448 sc0 sc1\n\t"
        "global_load_dwordx4 %8,  %16, off offset:512 sc0 sc1\n\t"
        "global_load_dwordx4 %9,  %16, off offset:576 sc0 sc1\n\t"
        "global_load_dwordx4 %10, %16, off offset:640 sc0 sc1\n\t"
        "global_load_dwordx4 %11, %16, off offset:704 sc0 sc1\n\t"
        "global_load_dwordx4 %12, %16, off offset:768 sc0 sc1\n\t"
        "global_load_dwordx4 %13, %16, off offset:832 sc0 sc1\n\t"
        "global_load_dwordx4 %14, %16, off offset:896 sc0 sc1\n\t"
        "global_load_dwordx4 %15, %16, off offset:960 sc0 sc1\n\t"
        "s_waitcnt vmcnt(0)"
        : "=v"(a0),"=v"(a1),"=v"(a2),"=v"(a3),"=v"(a4),"=v"(a5),"=v"(a6),"=v"(a7),
          "=v"(a8),"=v"(a9),"=v"(a10),"=v"(a11),"=v"(a12),"=v"(a13),"=v"(a14),"=v"(a15)
        : "v"(hbp)
        : "memory");
    }
    #define RETRY(A, OFF) \
      while (__builtin_expect(A.x==SENTI || A.y==SENTI || A.z==SENTI || A.w==SENTI, 0)) \
        A = poll16(hbp + (OFF), fast);
    RETRY(a0,0)    RETRY(a1,64)   RETRY(a2,128)  RETRY(a3,192)
    RETRY(a4,256)  RETRY(a5,320)  RETRY(a6,384)  RETRY(a7,448)
    RETRY(a8,512)  RETRY(a9,576)  RETRY(a10,640) RETRY(a11,704)
    RETRY(a12,768) RETRY(a13,832) RETRY(a14,896) RETRY(a15,960)
    #undef RETRY

    // (b) issue prefetch of next step's gx (consumed next iteration)
    if (t < 127){
      #pragma unroll
      for (int rep=0;rep<8;rep++){
        int idx = rep*256 + tid;
        int b = idx >> 7, jl = idx & 127;
        gr[rep] = gxT[(long)((t+1)*16 + b)*2048 + (jl>>5)*512 + p*32 + (jl&31)];
      }
    }

    // (c) MFMA: h chunks (registers) x W_hh fragments (LDS)
    floatx4 acc0 = {0.f,0.f,0.f,0.f};
    floatx4 acc1 = {0.f,0.f,0.f,0.f};
    #define STEPK(K, AK) { \
      short8 av = __builtin_bit_cast(short8, AK); \
      acc0 = __builtin_amdgcn_mfma_f32_16x16x32_bf16(av, wlds[(w2*16+(K))*64 + l], acc0, 0,0,0); \
      acc1 = __builtin_amdgcn_mfma_f32_16x16x32_bf16(av, wlds[((w2+1)*16+(K))*64 + l], acc1, 0,0,0); }
    STEPK(0,a0)   STEPK(1,a1)   STEPK(2,a2)   STEPK(3,a3)
    STEPK(4,a4)   STEPK(5,a5)   STEPK(6,a6)   STEPK(7,a7)
    STEPK(8,a8)   STEPK(9,a9)   STEPK(10,a10) STEPK(11,a11)
    STEPK(12,a12) STEPK(13,a13) STEPK(14,a14) STEPK(15,a15)
    #undef STEPK
    __syncthreads();

    // (d) accumulate fragments into gates
    #pragma unroll
    for (int r=0; r<4; r++){
      int bb = (l>>4)*4 + r;
      gx_sh[bb*128 + w*32 + (l&15)]      += acc0[r];
      gx_sh[bb*128 + w*32 + 16 + (l&15)] += acc1[r];
    }
    __syncthreads();

    // (e) activations: 2 batches per thread; hsh first so publish can go early
    float hout0, hout1;
    int row0, row1;
    {
      float ig = gx_sh[b0i*128 + u],      fg = gx_sh[b0i*128 + 32 + u];
      float gg = gx_sh[b0i*128 + 64 + u], og = gx_sh[b0i*128 + 96 + u];
      bool valid = (t < lens[b0i]);
      float ii = 1.f/(1.f+__expf(-ig)), ff = 1.f/(1.f+__expf(-fg));
      float g2 = ftanh(gg),             oo = 1.f/(1.f+__expf(-og));
      float cn = ff*c_r0 + ii*g2;
      float hn = oo*ftanh(cn);
      if (valid){ c_r0 = cn; h_r0 = hn; }
      hout0 = valid ? hn : 0.0f;
      hsh[b0i*32 + u] = f2b(h_r0);
      row0 = b0i*128 + t;
    }
    {
      float ig = gx_sh[b1i*128 + u],      fg = gx_sh[b1i*128 + 32 + u];
      float gg = gx_sh[b1i*128 + 64 + u], og = gx_sh[b1i*128 + 96 + u];
      bool valid = (t < lens[b1i]);
      float ii = 1.f/(1.f+__expf(-ig)), ff = 1.f/(1.f+__expf(-fg));
      float g2 = ftanh(gg),             oo = 1.f/(1.f+__expf(-og));
      float cn = ff*c_r1 + ii*g2;
      float hn = oo*ftanh(cn);
      if (valid){ c_r1 = cn; h_r1 = hn; }
      hout1 = valid ? hn : 0.0f;
      hsh[b1i*32 + u] = f2b(h_r1);
      row1 = b1i*128 + t;
    }
    __syncthreads();   // hsh ready

    // (f) publish h slice to slot t+1 FIRST (cross-block critical path)
    if (t < 127 && tid < 64){
      int b = tid >> 2, ch = tid & 3;
      intx4 hv = *(const intx4*)(hsh + b*32 + ch*8);
      bf16* dst = hbuf + (long)(t+1)*8192 + b*512 + p*32 + ch*8;
      if (fast)
        asm volatile("global_store_dwordx4 %0, %1, off sc0" :: "v"(dst), "v"(hv) : "memory");
      else
        asm volatile("global_store_dwordx4 %0, %1, off sc0 sc1" :: "v"(dst), "v"(hv) : "memory");
    }

    // (g) output stores (off the cross-block critical path)
    att_ws[(long)row0*1536 + p*32 + u]   = f2b(hout0);
    align_in[(long)row0*1024 + p*32 + u] = f2b(hout0);
    att_ws[(long)row1*1536 + p*32 + u]   = f2b(hout1);
    align_in[(long)row1*1024 + p*32 + u] = f2b(hout1);
  }
}

// ---------------------------------------------------- final att/targets out
__global__ void k_finout(const bf16* __restrict__ att_ws, const int* __restrict__ flags,
                         void* __restrict__ d_out){
  int f32 = flags[0];
  long i = (long)blockIdx.x*256 + threadIdx.x;  // 3,147,776 total
  if (i < 3145728){
    if (f32) ((float*)d_out)[65536000 + i] = b2f(att_ws[i]);
    else     ((bf16*)d_out)[65536000 + i] = att_ws[i];
  } else if (i < 3147776){
    long j = i - 3145728;
    float tv = (float)(4*((int)j & 127));
    if (f32) ((float*)d_out)[68681728 + j] = tv;
    else     ((bf16*)d_out)[68681728 + j] = f2b(tv);
  }
}

// ---------------------------------------------------------------- launch
extern "C" void kernel_launch(void* const* d_in, const int* in_sizes, int n_in,
                              void* d_out, int out_size, void* d_ws, size_t ws_size,
                              hipStream_t stream){
  const int*  x      = (const int*) d_in[0];
  const int*  xlen   = (const int*) d_in[1];
  const void* h0     = d_in[2];
  const void* c0     = d_in[3];
  const void* eo     = d_in[4];
  const void* emb    = d_in[5];
  const void* W_att  = d_in[6];
  const void* b_att  = d_in[7];
  const void* W_ih   = d_in[8];
  const void* W_hh   = d_in[9];
  const void* b_ih   = d_in[10];
  const void* b_hh   = d_in[11];
  const void* W_align= d_in[12];
  const void* b_align= d_in[13];
  const void* W_out  = d_in[14];
  const void* b_out  = d_in[15];

  char* ws = (char*)d_ws;
  bf16*  lstm_input = (bf16*)(ws + 0);            //  4,194,304
  bf16*  encT       = (bf16*)(ws + 4194304);      //  8,388,608
  bf16*  WattT      = (bf16*)(ws + 12582912);     //  1,572,864
  bf16*  WalignT    = (bf16*)(ws + 14155776);     //  1,048,576
  bf16*  WoutT      = (bf16*)(ws + 15204352);     // 32,768,000
  bf16*  Wsw        = (bf16*)(ws + 47972352);     //  2,097,152
  float* gxT        = (float*)(ws + 50069504);    // 16,777,216
  float* attlog     = (float*)(ws + 66846720);    //  4,194,304
  bf16*  soft       = (bf16*)(ws + 71041024);     //  2,097,152
  bf16*  align_in   = (bf16*)(ws + 73138176);     //  4,194,304
  // h history (128 slots x 16KB = 2MB) shares the final_in region:
  // written by k_prep (slot0) + k_sent (sentinels) + k_lstm; final_in is
  // produced only AFTER k_lstm by the M_ALIGN gemm -> lifetimes disjoint.
  bf16*  final_in   = (bf16*)(ws + 77332480);     //  2,097,152
  bf16*  hbuf       = (bf16*)(ws + 77332480);     //  (aliases final_in)
  bf16*  att_ws     = (bf16*)(ws + 79429632);     //  6,291,456
  bf16*  bb         = (bf16*)(ws + 85721088);     //     74,240
  float* state0     = (float*)(ws + 85795328);    //     65,536
  bf16*  WihB       = (bf16*)(ws + 85893632);     //  4,194,304
  int*   flags      = (int*) (ws + 90087936);     // total ~90.1 MB

  k_detect<<<1, 64, 0, stream>>>((const unsigned short*)h0, flags);
  k_prep<<<8192, 256, 0, stream>>>(x, h0, c0, emb, flags, lstm_input, att_ws, state0, hbuf);
  k_sent<<<2032, 256, 0, stream>>>((int*)hbuf);
  k_cvt<<<146, 256, 0, stream>>>(b_ih, b_hh, b_att, b_align, b_out, flags, bb);
  k_cvtW<<<8192, 256, 0, stream>>>(W_ih, flags, WihB, 2097152L);
  k_encT<<<dim3(16,16,16), dim3(32,8), 0, stream>>>(eo, flags, encT);
  k_tr<<<dim3(16,48),  dim3(32,8), 0, stream>>>(W_att,   WattT,   1536, 512, flags);
  k_tr<<<dim3(16,32),  dim3(32,8), 0, stream>>>(W_align, WalignT, 1024, 512, flags);
  k_tr<<<dim3(1000,16),dim3(32,8), 0, stream>>>(W_out,   WoutT,   512, 32000, flags);
  k_wswz<<<2048, 64, 0, stream>>>(W_hh, flags, Wsw);

  // gates_x = lstm_input @ W_ih^T + b_ih + b_hh  -> gxT[t*16+b][2048] f32
  k_gemm<M_GX><<<dim3(16,16,1), 256, 0, stream>>>(lstm_input, WihB, 1024,
      gxT, nullptr, nullptr, 0, bb, bb+2048, nullptr, nullptr, flags, 0, 0, 0);

  k_lstm<<<256, 256, 0, stream>>>(gxT, Wsw, xlen, state0, hbuf, flags, att_ws, align_in);

  // att_logits = attention_input @ W_att + b_att  (f32)
  k_gemm<M_F32><<<dim3(16,4,1), 256, 0, stream>>>(att_ws, WattT, 1536,
      attlog, nullptr, nullptr, 512, bb+4096, nullptr, nullptr, nullptr, flags, 0, 0, 0);

  k_softmax<<<2048, 256, 0, stream>>>(attlog, soft);

  // h_t_bar[b] = soft[b] @ enc[b]  -> align_in cols 512:1024
  k_gemm<M_BF16><<<dim3(1,4,16), 256, 0, stream>>>(soft, encT, 512,
      nullptr, align_in + 512, nullptr, 1024, nullptr, nullptr, nullptr, nullptr,
      flags, 65536L, 262144L, 131072L);

  // aligned = sigmoid(align_in @ W_align + b_align); final_in = lo + hb*aligned
  k_gemm<M_ALIGN><<<dim3(16,4,1), 256, 0, stream>>>(align_in, WalignT, 1024,
      nullptr, nullptr, nullptr, 0, bb+4608, nullptr, align_in, final_in, flags, 0, 0, 0);

  // out = final_in @ W_out + b_out
  k_gemm<M_OUT><<<dim3(16,250,1), 256, 0, stream>>>(final_in, WoutT, 512,
      nullptr, nullptr, d_out, 32000, bb+5120, nullptr, nullptr, nullptr, flags, 0, 0, 0);

  k_finout<<<12296, 256, 0, stream>>>(att_ws, flags, d_out);
}